// Round 6
// baseline (13636.911 us; speedup 1.0000x reference)
//
#include <hip/hip_runtime.h>
#include <cstdint>
#include <cstddef>

#define NB 4096
#define NN 64
#define LDP 68   // reconstruction kernels: LDS stride (16B-aligned cols, bank-spread)
#define LD2 65   // single-block kernels: LDS stride (scalar access, conflict-free)

// ---- workspace float offsets ----
#define OFF_MEAN  0
#define OFF_MS    4096
#define OFF_MIS   8192
#define OFF_LINV  12288
#define OFF_LB    16384
#define OFF_VAR   20480
#define OFF_SLOTS 24576
#define NSLOTS    64
#define OFF_Q     (OFF_SLOTS + NSLOTS*4096)        // 286720
#define OFF_LAM   (OFF_Q + (size_t)NB*4096)
#define WS_FULL   (OFF_LAM + (size_t)NB*64)
#define WS_ZERO_FLOATS (OFF_SLOTS + NSLOTS*4096)

__device__ __forceinline__ float bperm(int pad, float v){
  return __int_as_float(__builtin_amdgcn_ds_bpermute(pad, __float_as_int(v)));
}

// =====================================================================
// Register-resident one-sided Jacobi, two-pass chunked exchange.
// Lane t owns column t in col[64]. XOR pair ordering. Per round:
//   pass 1: partner column fetched in chunks of 8 (ds_bpermute), dot -> apq.
//           Live partner regs <= 8 -> total live ~95 VGPR: spills impossible
//           (R3-R5 profile: compiler spilled pc[64] to scratch at any size,
//            pinning occupancy at ~7 waves/CU and dur at ~2200us).
//   pass 2 (only when __any lane rotates; wave-uniform -> bperm exec-safe):
//           re-fetch chunks of 8, rotate in place. Lockstep guarantees all
//           lanes read chunk jb before any lane overwrites it.
// Norms tracked analytically; exact recompute at the end.
// =====================================================================
__device__ __forceinline__ void jacobi64(float col[64], float& nrm,
                                         const int maxsweep, const float tolsq) {
  const int lane = threadIdx.x & 63;
  {
    float n0=0.f,n1=0.f,n2=0.f,n3=0.f;
#pragma unroll
    for (int j=0;j<64;j+=4){
      n0=fmaf(col[j+0],col[j+0],n0); n1=fmaf(col[j+1],col[j+1],n1);
      n2=fmaf(col[j+2],col[j+2],n2); n3=fmaf(col[j+3],col[j+3],n3);
    }
    nrm=(n0+n1)+(n2+n3);
  }
#pragma unroll 1
  for (int sw=0; sw<maxsweep; ++sw){
    int anyrot=0;
#pragma unroll 1
    for (int m=1; m<64; ++m){
      const int pad = ((lane ^ m) << 2);
      float pn = bperm(pad, nrm);
      float a0=0.f,a1=0.f,a2=0.f,a3=0.f;
#pragma unroll
      for (int jb=0; jb<64; jb+=8){
        float p0=bperm(pad,col[jb+0]);
        float p1=bperm(pad,col[jb+1]);
        float p2=bperm(pad,col[jb+2]);
        float p3=bperm(pad,col[jb+3]);
        float p4=bperm(pad,col[jb+4]);
        float p5=bperm(pad,col[jb+5]);
        float p6=bperm(pad,col[jb+6]);
        float p7=bperm(pad,col[jb+7]);
        a0=fmaf(col[jb+0],p0,a0); a1=fmaf(col[jb+1],p1,a1);
        a2=fmaf(col[jb+2],p2,a2); a3=fmaf(col[jb+3],p3,a3);
        a0=fmaf(col[jb+4],p4,a0); a1=fmaf(col[jb+5],p5,a1);
        a2=fmaf(col[jb+6],p6,a2); a3=fmaf(col[jb+7],p7,a3);
      }
      float apq=(a0+a1)+(a2+a3);
      const bool isP = lane < (lane ^ m);
      float app = isP ? nrm : pn;
      float aqq = isP ? pn : nrm;
      const bool rot = (apq*apq > tolsq*app*aqq);
      if (__any((int)rot)){
        float tau = (aqq - app) / (2.0f*apq);
        float tt  = 1.0f / (fabsf(tau) + sqrtf(fmaf(tau,tau,1.0f)));
        tt = (tau < 0.0f) ? -tt : tt;
        float cc = rsqrtf(fmaf(tt,tt,1.0f));
        float ss = cc*tt;
        // identity rotation for lanes whose pair is below threshold
        float ccv = rot ? cc : 1.0f;
        float sgv = rot ? (isP ? -ss : ss) : 0.0f;
#pragma unroll
        for (int jb=0; jb<64; jb+=8){
          float p0=bperm(pad,col[jb+0]);
          float p1=bperm(pad,col[jb+1]);
          float p2=bperm(pad,col[jb+2]);
          float p3=bperm(pad,col[jb+3]);
          float p4=bperm(pad,col[jb+4]);
          float p5=bperm(pad,col[jb+5]);
          float p6=bperm(pad,col[jb+6]);
          float p7=bperm(pad,col[jb+7]);
          col[jb+0]=fmaf(ccv,col[jb+0],sgv*p0);
          col[jb+1]=fmaf(ccv,col[jb+1],sgv*p1);
          col[jb+2]=fmaf(ccv,col[jb+2],sgv*p2);
          col[jb+3]=fmaf(ccv,col[jb+3],sgv*p3);
          col[jb+4]=fmaf(ccv,col[jb+4],sgv*p4);
          col[jb+5]=fmaf(ccv,col[jb+5],sgv*p5);
          col[jb+6]=fmaf(ccv,col[jb+6],sgv*p6);
          col[jb+7]=fmaf(ccv,col[jb+7],sgv*p7);
        }
        float tq = tt*apq;
        nrm += rot ? (isP ? -tq : tq) : 0.0f;
        anyrot = 1;
      }
    }
    if (!__any(anyrot)) break;
  }
  // exact norms at the end
  {
    float n0=0.f,n1=0.f,n2=0.f,n3=0.f;
#pragma unroll
    for (int j=0;j<64;j+=4){
      n0=fmaf(col[j+0],col[j+0],n0); n1=fmaf(col[j+1],col[j+1],n1);
      n2=fmaf(col[j+2],col[j+2],n2); n3=fmaf(col[j+3],col[j+3],n3);
    }
    nrm=(n0+n1)+(n2+n3);
  }
}

// =====================================================================
// LDS-free congruence: col = (M * Xb * M^T) column t = M * (Xb * m_t).
// Xb/M element loads are wave-uniform -> scalar pipe; z blocked 4-wide.
// =====================================================================
__device__ __forceinline__ void cong_cols(const float* __restrict__ Xb,
                                          const float* __restrict__ M,
                                          float col[64], const int t){
  float mrow[64];
#pragma unroll
  for (int j=0;j<16;j++){
    float4 v = *reinterpret_cast<const float4*>(M + t*64 + 4*j);
    mrow[4*j+0]=v.x; mrow[4*j+1]=v.y; mrow[4*j+2]=v.z; mrow[4*j+3]=v.w;
  }
#pragma unroll
  for (int i=0;i<64;i++) col[i]=0.f;
#pragma unroll 1
  for (int kb=0;kb<16;kb++){
    const float* xr = Xb + kb*256;
    float z0=0.f,z1=0.f,z2=0.f,z3=0.f;
#pragma unroll
    for (int j=0;j<64;j++){
      float mj = mrow[j];
      z0 = fmaf(xr[      j], mj, z0);
      z1 = fmaf(xr[ 64 + j], mj, z1);
      z2 = fmaf(xr[128 + j], mj, z2);
      z3 = fmaf(xr[192 + j], mj, z3);
    }
    const float* mc = M + 4*kb;
#pragma unroll
    for (int i=0;i<64;i++){
      float c = col[i];
      c = fmaf(mc[i*64+0], z0, c);
      c = fmaf(mc[i*64+1], z1, c);
      c = fmaf(mc[i*64+2], z2, c);
      c = fmaf(mc[i*64+3], z3, c);
      col[i] = c;
    }
  }
}

// ================= K1: batch mean =================
__global__ __launch_bounds__(256) void k_mean(const float* __restrict__ X, float* __restrict__ meanAcc){
  const int tid=threadIdx.x; const int blk=blockIdx.x;
  float acc[16];
#pragma unroll
  for (int j=0;j<16;j++) acc[j]=0.f;
  const float* p = X + (size_t)blk*32*4096;
  for (int b2=0;b2<32;b2++){
#pragma unroll
    for (int j=0;j<16;j++) acc[j] += p[(size_t)b2*4096 + tid + 256*j];
  }
#pragma unroll
  for (int j=0;j<16;j++) atomicAdd(&meanAcc[tid+256*j], acc[j]*(1.0f/4096.0f));
}

// ================= 256-thread LDS matmul (col-major, stride LD2) =================
template<int MODE>
__device__ __forceinline__ void mmc256(float* __restrict__ dst, const float* __restrict__ A,
                                       const float* __restrict__ B, const float p0){
  const int tid=threadIdx.x; const int t=tid&63; const int i0=(tid>>6)*16;
  float acc[16];
#pragma unroll
  for (int j=0;j<16;j++) acc[j]=0.f;
#pragma unroll 4
  for (int k=0;k<64;k++){
    float bk = B[t*LD2+k];
#pragma unroll
    for (int j=0;j<16;j++) acc[j] = fmaf(A[k*LD2+i0+j], bk, acc[j]);
  }
  __syncthreads();
#pragma unroll
  for (int j=0;j<16;j++){
    int i=i0+j;
    float v=acc[j];
    if (MODE==1) v*=0.5f;
    if (MODE==2) v = ((i==t)?3.0f:0.0f) - v;
    if (MODE==3) v = v + ((i==t)?p0:0.0f);
    dst[t*LD2+i]=v;
  }
  __syncthreads();
}

__device__ __forceinline__ void chol_lds(float* __restrict__ C, const int tid, const int t, const int g){
  for (int j=0;j<64;j++){
    if (tid<64){
      float ljj = sqrtf(C[j*LD2+j]);
      float rinv = 1.0f/ljj;
      if (tid>=j) C[j*LD2+tid] = (tid==j)? ljj : C[j*LD2+tid]*rinv;
    }
    __syncthreads();
    for (int c=j+1+g; c<64; c+=4){
      float ljc = C[j*LD2+c];
      if (t>=c) C[c*LD2+t] -= C[j*LD2+t]*ljc;
    }
    __syncthreads();
  }
}

// ================= K2: Ms = mean^{1/2}, Mis = mean^{-1/2} via Newton-Schulz ====
__global__ __launch_bounds__(256) void k_sqrtmean(const float* __restrict__ meanw,
                                                  float* __restrict__ Msg, float* __restrict__ Misg){
  __shared__ float bufY[64*LD2], bufZ[64*LD2], bufT[64*LD2];
  const int tid=threadIdx.x;
  float tr=0.f;
  for (int k=0;k<64;k++) tr += meanw[k*65];
  const float alpha = 64.0f/tr;
  for (int e=tid; e<4096; e+=256){
    int r=e>>6, c=e&63;
    bufY[c*LD2+r] = alpha*meanw[e];
    bufZ[c*LD2+r] = (r==c)?1.0f:0.0f;
  }
  __syncthreads();
  float *pY=bufY, *pZ=bufZ, *pT=bufT;
  for (int it=0; it<5; ++it){
    mmc256<2>(pT, pZ, pY, 0.f);   // T = 3I - Z*Y
    mmc256<1>(pZ, pT, pZ, 0.f);   // Z' = 0.5*T*Z
    mmc256<1>(pT, pY, pT, 0.f);   // Y' = 0.5*Y*T
    float* tm=pY; pY=pT; pT=tm;
  }
  const float sa = sqrtf(alpha);
  const float isa = 1.0f/sa;
  for (int e=tid; e<4096; e+=256){
    int r=e>>6, c=e&63;
    Msg[e]  = pY[c*LD2+r]*isa;
    Misg[e] = pZ[c*LD2+r]*sa;
  }
}

// ================= K3: accumulate log(Mis X Mis) into slots =================
// 128 threads = 2 independent waves, 2 matrices per block.
__global__ __launch_bounds__(128,8) void k_logaccum(const float* __restrict__ X,
                                                    const float* __restrict__ Mis,
                                                    float* __restrict__ slots){
  __shared__ __align__(16) float Wc[2][64*LDP];
  __shared__ float wcoef[2][64];
  const int t=threadIdx.x & 63; const int wid=threadIdx.x>>6;
  const int b=blockIdx.x*2+wid;
  float col[64]; float nrm;
  cong_cols(X + (size_t)b*4096, Mis, col, t);
  jacobi64(col, nrm, 7, 1e-8f);
  // store W, share coeff log(lam)/lam^2
#pragma unroll
  for (int j=0;j<16;j++)
    *reinterpret_cast<float4*>(&Wc[wid][t*LDP+4*j]) = make_float4(col[4*j],col[4*j+1],col[4*j+2],col[4*j+3]);
  wcoef[wid][t] = 0.5f*logf(nrm)/nrm;
  __syncthreads();
  float acc[64];
#pragma unroll
  for (int i=0;i<64;i++) acc[i]=0.f;
#pragma unroll 1
  for (int k=0;k<64;k++){
    float f = wcoef[wid][k]*Wc[wid][k*LDP+t];
#pragma unroll
    for (int jj=0;jj<16;jj++){
      float4 a = *reinterpret_cast<const float4*>(&Wc[wid][k*LDP+4*jj]);
      acc[4*jj+0]=fmaf(a.x,f,acc[4*jj+0]); acc[4*jj+1]=fmaf(a.y,f,acc[4*jj+1]);
      acc[4*jj+2]=fmaf(a.z,f,acc[4*jj+2]); acc[4*jj+3]=fmaf(a.w,f,acc[4*jj+3]);
    }
  }
  float* dst = slots + (size_t)(b & (NSLOTS-1))*4096;
#pragma unroll
  for (int i=0;i<64;i++) atomicAdd(&dst[i*64+t], acc[i]);
}

// ================= K4: exp(tang), batch_mean, chol, Linv, Lb =================
__global__ __launch_bounds__(256) void k_mid(const float* __restrict__ slots,
                                             const float* __restrict__ Msg,
                                             const float* __restrict__ bias,
                                             float* __restrict__ Linvg, float* __restrict__ Lbg){
  __shared__ float b1[64*LD2], b2[64*LD2], b3[64*LD2];
  const int tid=threadIdx.x; const int t=tid&63; const int g=tid>>6;
  for (int e=tid; e<4096; e+=256){
    float s=0.f;
    for (int sl=0; sl<NSLOTS; ++sl) s += slots[(size_t)sl*4096+e];
    b1[(e&63)*LD2+(e>>6)] = s * (1.0f/(4096.0f*16.0f));
  }
  __syncthreads();
  for (int e=tid; e<4096; e+=256){
    int r=e>>6, c=e&63;
    b2[c*LD2+r] = (1.0f/40320.0f)*b1[c*LD2+r] + ((r==c)?(1.0f/5040.0f):0.0f);
  }
  __syncthreads();
  float *pR=b2, *pT=b3;
  const float cj0=1.f/720.f, cj1=1.f/120.f, cj2=1.f/24.f, cj3=1.f/6.f, cj4=0.5f, cj5=1.f, cj6=1.f;
  mmc256<3>(pT,b1,pR,cj0); { float* tm=pR; pR=pT; pT=tm; }
  mmc256<3>(pT,b1,pR,cj1); { float* tm=pR; pR=pT; pT=tm; }
  mmc256<3>(pT,b1,pR,cj2); { float* tm=pR; pR=pT; pT=tm; }
  mmc256<3>(pT,b1,pR,cj3); { float* tm=pR; pR=pT; pT=tm; }
  mmc256<3>(pT,b1,pR,cj4); { float* tm=pR; pR=pT; pT=tm; }
  mmc256<3>(pT,b1,pR,cj5); { float* tm=pR; pR=pT; pT=tm; }
  mmc256<3>(pT,b1,pR,cj6); { float* tm=pR; pR=pT; pT=tm; }
  for (int q=0;q<4;q++){ mmc256<0>(pT, pR, pR, 0.f); float* tm=pR; pR=pT; pT=tm; }
  for (int e=tid; e<4096; e+=256) b1[(e&63)*LD2+(e>>6)] = Msg[e];
  __syncthreads();
  mmc256<0>(pT, b1, pR, 0.f);
  mmc256<0>(pR, pT, b1, 0.f);
  chol_lds(pR, tid, t, g);
  if (tid<64){
    const int c=tid;
    for (int k=0;k<64;k++) pT[c*LD2+k]=0.f;
    for (int i=0;i<64;i++){
      float s = (i==c)?1.0f:0.0f;
      for (int k=0;k<i;k++) s -= pR[k*LD2+i]*pT[c*LD2+k];
      pT[c*LD2+i] = s / pR[i*LD2+i];
    }
  }
  __syncthreads();
  if (tid<64){
    const int c=tid;
    for (int i=0;i<64;i++) Linvg[i*64+c] = pT[c*LD2+i];
  }
  for (int e=tid; e<4096; e+=256) b1[(e&63)*LD2+(e>>6)] = bias[e];
  __syncthreads();
  chol_lds(b1, tid, t, g);
  if (tid<64){
    const int c=tid;
    for (int i=0;i<64;i++) Lbg[i*64+c] = (c<=i)? b1[c*LD2+i] : 0.0f;
  }
}

// ================= K5: Xc eig, var accumulation, optional store =================
// 128 threads = 2 waves = 2 matrices per block; no LDS.
template<bool STORE>
__global__ __launch_bounds__(128,8) void k_center(const float* __restrict__ X,
                                                  const float* __restrict__ Linv,
                                                  float* __restrict__ varAcc,
                                                  float* __restrict__ Qs, float* __restrict__ Ls){
  const int t=threadIdx.x & 63; const int wid=threadIdx.x>>6;
  const int b=blockIdx.x*2+wid;
  float col[64]; float nrm;
  cong_cols(X + (size_t)b*4096, Linv, col, t);
  jacobi64(col, nrm, 10, 1e-10f);
  float ll = 0.5f*logf(nrm);
  float f2 = ll*ll;
#pragma unroll
  for (int off=1; off<64; off<<=1) f2 += __shfl_xor(f2, off, 64);
  if (t==0) atomicAdd(varAcc, f2);
  if (STORE){
#pragma unroll
    for (int j=0;j<16;j++)
      *reinterpret_cast<float4*>(Qs + (size_t)b*4096 + t*64 + 4*j) =
          make_float4(col[4*j],col[4*j+1],col[4*j+2],col[4*j+3]);
    Ls[(size_t)b*64+t] = nrm;
  }
}

// ================= K7: Xs = sum lam^f q q^T ; out = Lb Xs Lb^T =================
// 128 threads = 2 waves = 2 matrices per block; per-wave LDS.
template<bool LOADW>
__global__ __launch_bounds__(128,8) void k_out(const float* __restrict__ X,
                                               const float* __restrict__ Linv,
                                               const float* __restrict__ Qs,
                                               const float* __restrict__ Ls,
                                               const float* __restrict__ Lb,
                                               const float* __restrict__ varAcc,
                                               const float* __restrict__ shift,
                                               float* __restrict__ out){
  __shared__ __align__(16) float Wc[2][64*LDP];
  __shared__ float wcoef[2][64];
  const int t=threadIdx.x & 63; const int wid=threadIdx.x>>6;
  const int b=blockIdx.x*2+wid;
  float col[64]; float nrm;
  if (LOADW){
#pragma unroll
    for (int j=0;j<16;j++){
      float4 v = *reinterpret_cast<const float4*>(Qs + (size_t)b*4096 + t*64 + 4*j);
      col[4*j+0]=v.x; col[4*j+1]=v.y; col[4*j+2]=v.z; col[4*j+3]=v.w;
    }
    nrm = Ls[(size_t)b*64+t];
  } else {
    cong_cols(X + (size_t)b*4096, Linv, col, t);
    jacobi64(col, nrm, 10, 1e-10f);
  }
  const float var = varAcc[0] * (1.0f/4096.0f);
  const float factor = shift[0] * rsqrtf(var + 1e-5f);
#pragma unroll
  for (int j=0;j<16;j++)
    *reinterpret_cast<float4*>(&Wc[wid][t*LDP+4*j]) = make_float4(col[4*j],col[4*j+1],col[4*j+2],col[4*j+3]);
  wcoef[wid][t] = expf((factor-2.0f)*0.5f*logf(nrm));   // lam^{f-2}
  __syncthreads();
  float acc[64];
#pragma unroll
  for (int i=0;i<64;i++) acc[i]=0.f;
#pragma unroll 1
  for (int k=0;k<64;k++){
    float f = wcoef[wid][k]*Wc[wid][k*LDP+t];
#pragma unroll
    for (int jj=0;jj<16;jj++){
      float4 a = *reinterpret_cast<const float4*>(&Wc[wid][k*LDP+4*jj]);
      acc[4*jj+0]=fmaf(a.x,f,acc[4*jj+0]); acc[4*jj+1]=fmaf(a.y,f,acc[4*jj+1]);
      acc[4*jj+2]=fmaf(a.z,f,acc[4*jj+2]); acc[4*jj+3]=fmaf(a.w,f,acc[4*jj+3]);
    }
  }
  __syncthreads();
  // T2 = Lb * Xs (col-major into Wc)
#pragma unroll 2
  for (int i=0;i<64;i++){
    float s0=0.f,s1=0.f;
#pragma unroll
    for (int k=0;k<64;k+=2){ s0=fmaf(Lb[i*64+k],acc[k],s0); s1=fmaf(Lb[i*64+k+1],acc[k+1],s1); }
    Wc[wid][t*LDP+i]=s0+s1;
  }
  __syncthreads();
  float o[64];
#pragma unroll
  for (int i=0;i<64;i++) o[i]=0.f;
#pragma unroll 1
  for (int k=0;k<64;k++){
    float bk = Lb[t*64+k];
#pragma unroll
    for (int jj=0;jj<16;jj++){
      float4 a = *reinterpret_cast<const float4*>(&Wc[wid][k*LDP+4*jj]);
      o[4*jj+0]=fmaf(a.x,bk,o[4*jj+0]); o[4*jj+1]=fmaf(a.y,bk,o[4*jj+1]);
      o[4*jj+2]=fmaf(a.z,bk,o[4*jj+2]); o[4*jj+3]=fmaf(a.w,bk,o[4*jj+3]);
    }
  }
  float* ob = out + (size_t)b*4096;
#pragma unroll
  for (int i=0;i<64;i++) ob[i*64+t] = o[i];
}

// =====================================================================
extern "C" void kernel_launch(void* const* d_in, const int* in_sizes, int n_in,
                              void* d_out, int out_size, void* d_ws, size_t ws_size,
                              hipStream_t stream){
  (void)in_sizes; (void)n_in; (void)out_size;
  const float* X     = (const float*)d_in[0];
  const float* bias  = (const float*)d_in[1];
  const float* shift = (const float*)d_in[2];
  float* out = (float*)d_out;
  float* ws  = (float*)d_ws;

  hipMemsetAsync(d_ws, 0, (size_t)WS_ZERO_FLOATS*sizeof(float), stream);
  k_mean<<<128,256,0,stream>>>(X, ws+OFF_MEAN);
  k_sqrtmean<<<1,256,0,stream>>>(ws+OFF_MEAN, ws+OFF_MS, ws+OFF_MIS);
  k_logaccum<<<NB/2,128,0,stream>>>(X, ws+OFF_MIS, ws+OFF_SLOTS);
  k_mid<<<1,256,0,stream>>>(ws+OFF_SLOTS, ws+OFF_MS, bias, ws+OFF_LINV, ws+OFF_LB);

  const bool big = ws_size >= (size_t)WS_FULL*sizeof(float);
  if (big){
    k_center<true><<<NB/2,128,0,stream>>>(X, ws+OFF_LINV, ws+OFF_VAR, ws+OFF_Q, ws+OFF_LAM);
    k_out<true><<<NB/2,128,0,stream>>>(X, ws+OFF_LINV, ws+OFF_Q, ws+OFF_LAM, ws+OFF_LB, ws+OFF_VAR, shift, out);
  } else {
    k_center<false><<<NB/2,128,0,stream>>>(X, ws+OFF_LINV, ws+OFF_VAR, nullptr, nullptr);
    k_out<false><<<NB/2,128,0,stream>>>(X, ws+OFF_LINV, nullptr, nullptr, ws+OFF_LB, ws+OFF_VAR, shift, out);
  }
}

// Round 7
// 4292.546 us; speedup vs baseline: 3.1769x; 3.1769x over previous
//
#include <hip/hip_runtime.h>
#include <cstdint>
#include <cstddef>

#define NB 4096
#define NN 64
#define LDP 68   // LDS stride: 272B = 16B-aligned AND t*17 mod 8 spreads lanes over all 8 bank-quads
#define LD2 65   // single-block kernels: LDS stride (scalar access, conflict-free)

// ---- workspace float offsets ----
#define OFF_MEAN  0
#define OFF_MS    4096
#define OFF_MIS   8192
#define OFF_LINV  12288
#define OFF_LB    16384
#define OFF_VAR   20480
#define OFF_SLOTS 24576
#define NSLOTS    64
#define OFF_Q     (OFF_SLOTS + NSLOTS*4096)        // 286720
#define OFF_LAM   (OFF_Q + (size_t)NB*4096)
#define WS_FULL   (OFF_LAM + (size_t)NB*64)
#define WS_ZERO_FLOATS (OFF_SLOTS + NSLOTS*4096)

__device__ __forceinline__ float bperm(int pad, float v){
  return __int_as_float(__builtin_amdgcn_ds_bpermute(pad, __float_as_int(v)));
}

// =====================================================================
// One-sided Jacobi with LDS master copy of W (col-major, stride LDP=68).
// Lane t owns column t in col[64] (registers); Wm mirrors the current
// state so partners read via ds_read_b128 (85-128 B/cyc) instead of
// ds_bpermute (27 B/cyc) -- the R3-R5 DS-throughput wall at 625 cyc/round.
// Per round: 16 b128 reads (partner col -> pc regs, streamed into dot),
// rotation, 16 b128 writes of own col (only if wave rotated), 1 bperm (nrm).
// Wave-private LDS: per-wave DS ordering + compiler lgkmcnt waits make the
// read-after-write across rounds safe. On exit: col = lambda_k q_k = Wm,
// nrm = lambda^2 (exact recompute).
// =====================================================================
__device__ __forceinline__ void jacobi64_lds(float col[64], float& nrm,
                                             float* __restrict__ Wm,
                                             const int t,
                                             const int maxsweep, const float tolsq) {
  // initial master write + norm
  {
#pragma unroll
    for (int jb=0;jb<16;jb++)
      *reinterpret_cast<float4*>(Wm + t*LDP + 4*jb) =
        make_float4(col[4*jb],col[4*jb+1],col[4*jb+2],col[4*jb+3]);
    float n0=0.f,n1=0.f,n2=0.f,n3=0.f;
#pragma unroll
    for (int j=0;j<64;j+=4){
      n0=fmaf(col[j+0],col[j+0],n0); n1=fmaf(col[j+1],col[j+1],n1);
      n2=fmaf(col[j+2],col[j+2],n2); n3=fmaf(col[j+3],col[j+3],n3);
    }
    nrm=(n0+n1)+(n2+n3);
  }
#pragma unroll 1
  for (int sw=0; sw<maxsweep; ++sw){
    int anyrot=0;
#pragma unroll 1
    for (int m=1; m<64; ++m){
      const int pad = ((t ^ m) << 2);
      const float* __restrict__ P = Wm + (t ^ m)*LDP;
      float pn = bperm(pad, nrm);
      // pass 1: stream partner column (b128) into dot, keep pc in regs
      float pc[64];
      float a0=0.f,a1=0.f,a2=0.f,a3=0.f;
#pragma unroll
      for (int jb=0;jb<16;jb++){
        float4 q = *reinterpret_cast<const float4*>(P + 4*jb);
        pc[4*jb+0]=q.x; pc[4*jb+1]=q.y; pc[4*jb+2]=q.z; pc[4*jb+3]=q.w;
        a0=fmaf(col[4*jb+0],q.x,a0); a1=fmaf(col[4*jb+1],q.y,a1);
        a2=fmaf(col[4*jb+2],q.z,a2); a3=fmaf(col[4*jb+3],q.w,a3);
      }
      float apq=(a0+a1)+(a2+a3);
      const bool isP = t < (t ^ m);
      float app = isP ? nrm : pn;
      float aqq = isP ? pn : nrm;
      const bool rot = (apq*apq > tolsq*app*aqq);
      if (__any((int)rot)){
        float tau = (aqq - app) / (2.0f*apq);
        float tt  = 1.0f / (fabsf(tau) + sqrtf(fmaf(tau,tau,1.0f)));
        tt = (tau < 0.0f) ? -tt : tt;
        float cc = rsqrtf(fmaf(tt,tt,1.0f));
        float ss = cc*tt;
        float ccv = rot ? cc : 1.0f;
        float sgv = rot ? (isP ? -ss : ss) : 0.0f;
#pragma unroll
        for (int j=0;j<64;j++) col[j] = fmaf(ccv, col[j], sgv*pc[j]);
        float tq = tt*apq;
        nrm += rot ? (isP ? -tq : tq) : 0.0f;
        // write back own column so future partners see it
#pragma unroll
        for (int jb=0;jb<16;jb++)
          *reinterpret_cast<float4*>(Wm + t*LDP + 4*jb) =
            make_float4(col[4*jb],col[4*jb+1],col[4*jb+2],col[4*jb+3]);
        anyrot = 1;
      }
    }
    if (!__any(anyrot)) break;
  }
  // exact norms at the end
  {
    float n0=0.f,n1=0.f,n2=0.f,n3=0.f;
#pragma unroll
    for (int j=0;j<64;j+=4){
      n0=fmaf(col[j+0],col[j+0],n0); n1=fmaf(col[j+1],col[j+1],n1);
      n2=fmaf(col[j+2],col[j+2],n2); n3=fmaf(col[j+3],col[j+3],n3);
    }
    nrm=(n0+n1)+(n2+n3);
  }
}

// =====================================================================
// LDS-free congruence: col = (M * Xb * M^T) column t = M * (Xb * m_t).
// Xb/M element loads are wave-uniform -> scalar pipe; z blocked 4-wide.
// =====================================================================
__device__ __forceinline__ void cong_cols(const float* __restrict__ Xb,
                                          const float* __restrict__ M,
                                          float col[64], const int t){
  float mrow[64];
#pragma unroll
  for (int j=0;j<16;j++){
    float4 v = *reinterpret_cast<const float4*>(M + t*64 + 4*j);
    mrow[4*j+0]=v.x; mrow[4*j+1]=v.y; mrow[4*j+2]=v.z; mrow[4*j+3]=v.w;
  }
#pragma unroll
  for (int i=0;i<64;i++) col[i]=0.f;
#pragma unroll 1
  for (int kb=0;kb<16;kb++){
    const float* xr = Xb + kb*256;
    float z0=0.f,z1=0.f,z2=0.f,z3=0.f;
#pragma unroll
    for (int j=0;j<64;j++){
      float mj = mrow[j];
      z0 = fmaf(xr[      j], mj, z0);
      z1 = fmaf(xr[ 64 + j], mj, z1);
      z2 = fmaf(xr[128 + j], mj, z2);
      z3 = fmaf(xr[192 + j], mj, z3);
    }
    const float* mc = M + 4*kb;
#pragma unroll
    for (int i=0;i<64;i++){
      float c = col[i];
      c = fmaf(mc[i*64+0], z0, c);
      c = fmaf(mc[i*64+1], z1, c);
      c = fmaf(mc[i*64+2], z2, c);
      c = fmaf(mc[i*64+3], z3, c);
      col[i] = c;
    }
  }
}

// ================= K1: batch mean =================
__global__ __launch_bounds__(256) void k_mean(const float* __restrict__ X, float* __restrict__ meanAcc){
  const int tid=threadIdx.x; const int blk=blockIdx.x;
  float acc[16];
#pragma unroll
  for (int j=0;j<16;j++) acc[j]=0.f;
  const float* p = X + (size_t)blk*32*4096;
  for (int b2=0;b2<32;b2++){
#pragma unroll
    for (int j=0;j<16;j++) acc[j] += p[(size_t)b2*4096 + tid + 256*j];
  }
#pragma unroll
  for (int j=0;j<16;j++) atomicAdd(&meanAcc[tid+256*j], acc[j]*(1.0f/4096.0f));
}

// ================= 256-thread LDS matmul (col-major, stride LD2) =================
template<int MODE>
__device__ __forceinline__ void mmc256(float* __restrict__ dst, const float* __restrict__ A,
                                       const float* __restrict__ B, const float p0){
  const int tid=threadIdx.x; const int t=tid&63; const int i0=(tid>>6)*16;
  float acc[16];
#pragma unroll
  for (int j=0;j<16;j++) acc[j]=0.f;
#pragma unroll 4
  for (int k=0;k<64;k++){
    float bk = B[t*LD2+k];
#pragma unroll
    for (int j=0;j<16;j++) acc[j] = fmaf(A[k*LD2+i0+j], bk, acc[j]);
  }
  __syncthreads();
#pragma unroll
  for (int j=0;j<16;j++){
    int i=i0+j;
    float v=acc[j];
    if (MODE==1) v*=0.5f;
    if (MODE==2) v = ((i==t)?3.0f:0.0f) - v;
    if (MODE==3) v = v + ((i==t)?p0:0.0f);
    dst[t*LD2+i]=v;
  }
  __syncthreads();
}

__device__ __forceinline__ void chol_lds(float* __restrict__ C, const int tid, const int t, const int g){
  for (int j=0;j<64;j++){
    if (tid<64){
      float ljj = sqrtf(C[j*LD2+j]);
      float rinv = 1.0f/ljj;
      if (tid>=j) C[j*LD2+tid] = (tid==j)? ljj : C[j*LD2+tid]*rinv;
    }
    __syncthreads();
    for (int c=j+1+g; c<64; c+=4){
      float ljc = C[j*LD2+c];
      if (t>=c) C[c*LD2+t] -= C[j*LD2+t]*ljc;
    }
    __syncthreads();
  }
}

// ================= K2: Ms = mean^{1/2}, Mis = mean^{-1/2} via Newton-Schulz ====
__global__ __launch_bounds__(256) void k_sqrtmean(const float* __restrict__ meanw,
                                                  float* __restrict__ Msg, float* __restrict__ Misg){
  __shared__ float bufY[64*LD2], bufZ[64*LD2], bufT[64*LD2];
  const int tid=threadIdx.x;
  float tr=0.f;
  for (int k=0;k<64;k++) tr += meanw[k*65];
  const float alpha = 64.0f/tr;
  for (int e=tid; e<4096; e+=256){
    int r=e>>6, c=e&63;
    bufY[c*LD2+r] = alpha*meanw[e];
    bufZ[c*LD2+r] = (r==c)?1.0f:0.0f;
  }
  __syncthreads();
  float *pY=bufY, *pZ=bufZ, *pT=bufT;
  for (int it=0; it<5; ++it){
    mmc256<2>(pT, pZ, pY, 0.f);   // T = 3I - Z*Y
    mmc256<1>(pZ, pT, pZ, 0.f);   // Z' = 0.5*T*Z
    mmc256<1>(pT, pY, pT, 0.f);   // Y' = 0.5*Y*T
    float* tm=pY; pY=pT; pT=tm;
  }
  const float sa = sqrtf(alpha);
  const float isa = 1.0f/sa;
  for (int e=tid; e<4096; e+=256){
    int r=e>>6, c=e&63;
    Msg[e]  = pY[c*LD2+r]*isa;
    Misg[e] = pZ[c*LD2+r]*sa;
  }
}

// ================= K3: accumulate log(Mis X Mis) into slots =================
// 1 wave per matrix; Jacobi master Wm doubles as the eigvec buffer Wc
// (same layout), so no separate store is needed.
__global__ __launch_bounds__(64,2) void k_logaccum(const float* __restrict__ X,
                                                   const float* __restrict__ Mis,
                                                   float* __restrict__ slots){
  __shared__ __align__(16) float Wm[64*LDP];
  __shared__ float wcoef[64];
  const int t=threadIdx.x & 63; const int b=blockIdx.x;
  float col[64]; float nrm;
  cong_cols(X + (size_t)b*4096, Mis, col, t);
  jacobi64_lds(col, nrm, Wm, t, 7, 1e-8f);
  wcoef[t] = 0.5f*logf(nrm)/nrm;
  float acc[64];
#pragma unroll
  for (int i=0;i<64;i++) acc[i]=0.f;
#pragma unroll 1
  for (int k=0;k<64;k++){
    float f = wcoef[k]*Wm[k*LDP+t];
#pragma unroll
    for (int jj=0;jj<16;jj++){
      float4 a = *reinterpret_cast<const float4*>(&Wm[k*LDP+4*jj]);
      acc[4*jj+0]=fmaf(a.x,f,acc[4*jj+0]); acc[4*jj+1]=fmaf(a.y,f,acc[4*jj+1]);
      acc[4*jj+2]=fmaf(a.z,f,acc[4*jj+2]); acc[4*jj+3]=fmaf(a.w,f,acc[4*jj+3]);
    }
  }
  float* dst = slots + (size_t)(b & (NSLOTS-1))*4096;
#pragma unroll
  for (int i=0;i<64;i++) atomicAdd(&dst[i*64+t], acc[i]);
}

// ================= K4: exp(tang), batch_mean, chol, Linv, Lb =================
__global__ __launch_bounds__(256) void k_mid(const float* __restrict__ slots,
                                             const float* __restrict__ Msg,
                                             const float* __restrict__ bias,
                                             float* __restrict__ Linvg, float* __restrict__ Lbg){
  __shared__ float b1[64*LD2], b2[64*LD2], b3[64*LD2];
  const int tid=threadIdx.x; const int t=tid&63; const int g=tid>>6;
  for (int e=tid; e<4096; e+=256){
    float s=0.f;
    for (int sl=0; sl<NSLOTS; ++sl) s += slots[(size_t)sl*4096+e];
    b1[(e&63)*LD2+(e>>6)] = s * (1.0f/(4096.0f*16.0f));
  }
  __syncthreads();
  for (int e=tid; e<4096; e+=256){
    int r=e>>6, c=e&63;
    b2[c*LD2+r] = (1.0f/40320.0f)*b1[c*LD2+r] + ((r==c)?(1.0f/5040.0f):0.0f);
  }
  __syncthreads();
  float *pR=b2, *pT=b3;
  const float cj0=1.f/720.f, cj1=1.f/120.f, cj2=1.f/24.f, cj3=1.f/6.f, cj4=0.5f, cj5=1.f, cj6=1.f;
  mmc256<3>(pT,b1,pR,cj0); { float* tm=pR; pR=pT; pT=tm; }
  mmc256<3>(pT,b1,pR,cj1); { float* tm=pR; pR=pT; pT=tm; }
  mmc256<3>(pT,b1,pR,cj2); { float* tm=pR; pR=pT; pT=tm; }
  mmc256<3>(pT,b1,pR,cj3); { float* tm=pR; pR=pT; pT=tm; }
  mmc256<3>(pT,b1,pR,cj4); { float* tm=pR; pR=pT; pT=tm; }
  mmc256<3>(pT,b1,pR,cj5); { float* tm=pR; pR=pT; pT=tm; }
  mmc256<3>(pT,b1,pR,cj6); { float* tm=pR; pR=pT; pT=tm; }
  for (int q=0;q<4;q++){ mmc256<0>(pT, pR, pR, 0.f); float* tm=pR; pR=pT; pT=tm; }
  for (int e=tid; e<4096; e+=256) b1[(e&63)*LD2+(e>>6)] = Msg[e];
  __syncthreads();
  mmc256<0>(pT, b1, pR, 0.f);
  mmc256<0>(pR, pT, b1, 0.f);
  chol_lds(pR, tid, t, g);
  if (tid<64){
    const int c=tid;
    for (int k=0;k<64;k++) pT[c*LD2+k]=0.f;
    for (int i=0;i<64;i++){
      float s = (i==c)?1.0f:0.0f;
      for (int k=0;k<i;k++) s -= pR[k*LD2+i]*pT[c*LD2+k];
      pT[c*LD2+i] = s / pR[i*LD2+i];
    }
  }
  __syncthreads();
  if (tid<64){
    const int c=tid;
    for (int i=0;i<64;i++) Linvg[i*64+c] = pT[c*LD2+i];
  }
  for (int e=tid; e<4096; e+=256) b1[(e&63)*LD2+(e>>6)] = bias[e];
  __syncthreads();
  chol_lds(b1, tid, t, g);
  if (tid<64){
    const int c=tid;
    for (int i=0;i<64;i++) Lbg[i*64+c] = (c<=i)? b1[c*LD2+i] : 0.0f;
  }
}

// ================= K5: Xc eig, var accumulation, optional store =================
template<bool STORE>
__global__ __launch_bounds__(64,2) void k_center(const float* __restrict__ X,
                                                 const float* __restrict__ Linv,
                                                 float* __restrict__ varAcc,
                                                 float* __restrict__ Qs, float* __restrict__ Ls){
  __shared__ __align__(16) float Wm[64*LDP];
  const int t=threadIdx.x & 63; const int b=blockIdx.x;
  float col[64]; float nrm;
  cong_cols(X + (size_t)b*4096, Linv, col, t);
  jacobi64_lds(col, nrm, Wm, t, 10, 1e-10f);
  float ll = 0.5f*logf(nrm);
  float f2 = ll*ll;
#pragma unroll
  for (int off=1; off<64; off<<=1) f2 += __shfl_xor(f2, off, 64);
  if (t==0) atomicAdd(varAcc, f2);
  if (STORE){
#pragma unroll
    for (int j=0;j<16;j++)
      *reinterpret_cast<float4*>(Qs + (size_t)b*4096 + t*64 + 4*j) =
          make_float4(col[4*j],col[4*j+1],col[4*j+2],col[4*j+3]);
    Ls[(size_t)b*64+t] = nrm;
  }
}

// ================= K7: Xs = sum lam^f q q^T ; out = Lb Xs Lb^T =================
template<bool LOADW>
__global__ __launch_bounds__(64,2) void k_out(const float* __restrict__ X,
                                              const float* __restrict__ Linv,
                                              const float* __restrict__ Qs,
                                              const float* __restrict__ Ls,
                                              const float* __restrict__ Lb,
                                              const float* __restrict__ varAcc,
                                              const float* __restrict__ shift,
                                              float* __restrict__ out){
  __shared__ __align__(16) float Wm[64*LDP];
  __shared__ float wcoef[64];
  const int t=threadIdx.x & 63; const int b=blockIdx.x;
  float col[64]; float nrm;
  if (LOADW){
#pragma unroll
    for (int j=0;j<16;j++){
      float4 v = *reinterpret_cast<const float4*>(Qs + (size_t)b*4096 + t*64 + 4*j);
      col[4*j+0]=v.x; col[4*j+1]=v.y; col[4*j+2]=v.z; col[4*j+3]=v.w;
    }
    nrm = Ls[(size_t)b*64+t];
#pragma unroll
    for (int j=0;j<16;j++)
      *reinterpret_cast<float4*>(&Wm[t*LDP+4*j]) = make_float4(col[4*j],col[4*j+1],col[4*j+2],col[4*j+3]);
  } else {
    cong_cols(X + (size_t)b*4096, Linv, col, t);
    jacobi64_lds(col, nrm, Wm, t, 10, 1e-10f);   // Wm left holding eigvec columns
  }
  const float var = varAcc[0] * (1.0f/4096.0f);
  const float factor = shift[0] * rsqrtf(var + 1e-5f);
  wcoef[t] = expf((factor-2.0f)*0.5f*logf(nrm));   // lam^{f-2}
  float acc[64];
#pragma unroll
  for (int i=0;i<64;i++) acc[i]=0.f;
#pragma unroll 1
  for (int k=0;k<64;k++){
    float f = wcoef[k]*Wm[k*LDP+t];
#pragma unroll
    for (int jj=0;jj<16;jj++){
      float4 a = *reinterpret_cast<const float4*>(&Wm[k*LDP+4*jj]);
      acc[4*jj+0]=fmaf(a.x,f,acc[4*jj+0]); acc[4*jj+1]=fmaf(a.y,f,acc[4*jj+1]);
      acc[4*jj+2]=fmaf(a.z,f,acc[4*jj+2]); acc[4*jj+3]=fmaf(a.w,f,acc[4*jj+3]);
    }
  }
  // T2 = Lb * Xs (col-major into Wm; all reads of Wm above are complete
  // within this wave before the writes below -- single-wave block)
#pragma unroll 2
  for (int i=0;i<64;i++){
    float s0=0.f,s1=0.f;
#pragma unroll
    for (int k=0;k<64;k+=2){ s0=fmaf(Lb[i*64+k],acc[k],s0); s1=fmaf(Lb[i*64+k+1],acc[k+1],s1); }
    Wm[t*LDP+i]=s0+s1;
  }
  float o[64];
#pragma unroll
  for (int i=0;i<64;i++) o[i]=0.f;
#pragma unroll 1
  for (int k=0;k<64;k++){
    float bk = Lb[t*64+k];
#pragma unroll
    for (int jj=0;jj<16;jj++){
      float4 a = *reinterpret_cast<const float4*>(&Wm[k*LDP+4*jj]);
      o[4*jj+0]=fmaf(a.x,bk,o[4*jj+0]); o[4*jj+1]=fmaf(a.y,bk,o[4*jj+1]);
      o[4*jj+2]=fmaf(a.z,bk,o[4*jj+2]); o[4*jj+3]=fmaf(a.w,bk,o[4*jj+3]);
    }
  }
  float* ob = out + (size_t)b*4096;
#pragma unroll
  for (int i=0;i<64;i++) ob[i*64+t] = o[i];
}

// =====================================================================
extern "C" void kernel_launch(void* const* d_in, const int* in_sizes, int n_in,
                              void* d_out, int out_size, void* d_ws, size_t ws_size,
                              hipStream_t stream){
  (void)in_sizes; (void)n_in; (void)out_size;
  const float* X     = (const float*)d_in[0];
  const float* bias  = (const float*)d_in[1];
  const float* shift = (const float*)d_in[2];
  float* out = (float*)d_out;
  float* ws  = (float*)d_ws;

  hipMemsetAsync(d_ws, 0, (size_t)WS_ZERO_FLOATS*sizeof(float), stream);
  k_mean<<<128,256,0,stream>>>(X, ws+OFF_MEAN);
  k_sqrtmean<<<1,256,0,stream>>>(ws+OFF_MEAN, ws+OFF_MS, ws+OFF_MIS);
  k_logaccum<<<NB,64,0,stream>>>(X, ws+OFF_MIS, ws+OFF_SLOTS);
  k_mid<<<1,256,0,stream>>>(ws+OFF_SLOTS, ws+OFF_MS, bias, ws+OFF_LINV, ws+OFF_LB);

  const bool big = ws_size >= (size_t)WS_FULL*sizeof(float);
  if (big){
    k_center<true><<<NB,64,0,stream>>>(X, ws+OFF_LINV, ws+OFF_VAR, ws+OFF_Q, ws+OFF_LAM);
    k_out<true><<<NB,64,0,stream>>>(X, ws+OFF_LINV, ws+OFF_Q, ws+OFF_LAM, ws+OFF_LB, ws+OFF_VAR, shift, out);
  } else {
    k_center<false><<<NB,64,0,stream>>>(X, ws+OFF_LINV, ws+OFF_VAR, nullptr, nullptr);
    k_out<false><<<NB,64,0,stream>>>(X, ws+OFF_LINV, nullptr, nullptr, ws+OFF_LB, ws+OFF_VAR, shift, out);
  }
}

// Round 8
// 4276.289 us; speedup vs baseline: 3.1890x; 1.0038x over previous
//
#include <hip/hip_runtime.h>
#include <cstdint>
#include <cstddef>

#define NB 4096
#define NN 64
#define LDP 68   // LDS stride: 272B = 16B-aligned, t*17 mod 8 spreads lanes over bank-quads
#define LD2 65   // single-block kernels: LDS stride (scalar access, conflict-free)

// ---- workspace float offsets ----
#define OFF_MEAN  0
#define OFF_MS    4096
#define OFF_MIS   8192
#define OFF_LINV  12288
#define OFF_LB    16384
#define OFF_VAR   20480
#define OFF_SLOTS 24576
#define NSLOTS    64
#define OFF_Q     (OFF_SLOTS + NSLOTS*4096)        // 286720
#define OFF_LAM   (OFF_Q + (size_t)NB*4096)
#define WS_FULL   (OFF_LAM + (size_t)NB*64)
#define WS_ZERO_FLOATS (OFF_SLOTS + NSLOTS*4096)

__device__ __forceinline__ float bperm(int pad, float v){
  return __int_as_float(__builtin_amdgcn_ds_bpermute(pad, __float_as_int(v)));
}

// =====================================================================
// One-sided Jacobi with LDS master copy of W (col-major, stride LDP=68).
// Lane t owns column t in col[64]; Wm mirrors current state; partner
// columns are read via 16x ds_read_b128. KEY FIX vs R7: an empty asm
// memory barrier between the partner-read and the rotation forbids the
// compiler from rematerializing pc[] by re-reading LDS (R7 profile:
// VGPR=76 -> rotate loop re-read all 16 b128, doubling DS traffic; the
// DS pipe is the saturated resource at ~5.8M cyc/CU). With pc pinned,
// a rotating round is 16 reads + <=16 conditional writes; a skipped
// round is 16 reads only. Write-back is per-lane conditional (exec-
// masked): non-rotating lanes' columns are unchanged in LDS.
// =====================================================================
__device__ __forceinline__ void jacobi64_lds(float col[64], float& nrm,
                                             float* __restrict__ Wm,
                                             const int t,
                                             const int maxsweep, const float tolsq) {
  // initial master write + norm
  {
#pragma unroll
    for (int jb=0;jb<16;jb++)
      *reinterpret_cast<float4*>(Wm + t*LDP + 4*jb) =
        make_float4(col[4*jb],col[4*jb+1],col[4*jb+2],col[4*jb+3]);
    float n0=0.f,n1=0.f,n2=0.f,n3=0.f;
#pragma unroll
    for (int j=0;j<64;j+=4){
      n0=fmaf(col[j+0],col[j+0],n0); n1=fmaf(col[j+1],col[j+1],n1);
      n2=fmaf(col[j+2],col[j+2],n2); n3=fmaf(col[j+3],col[j+3],n3);
    }
    nrm=(n0+n1)+(n2+n3);
  }
#pragma unroll 1
  for (int sw=0; sw<maxsweep; ++sw){
    int anyrot=0;
#pragma unroll 1
    for (int m=1; m<64; ++m){
      const int pad = ((t ^ m) << 2);
      const float* __restrict__ P = Wm + (t ^ m)*LDP;
      float pn = bperm(pad, nrm);
      // partner column -> pc regs, streamed into the dot
      float pc[64];
      float a0=0.f,a1=0.f,a2=0.f,a3=0.f;
#pragma unroll
      for (int jb=0;jb<16;jb++){
        float4 q = *reinterpret_cast<const float4*>(P + 4*jb);
        pc[4*jb+0]=q.x; pc[4*jb+1]=q.y; pc[4*jb+2]=q.z; pc[4*jb+3]=q.w;
        a0=fmaf(col[4*jb+0],q.x,a0); a1=fmaf(col[4*jb+1],q.y,a1);
        a2=fmaf(col[4*jb+2],q.z,a2); a3=fmaf(col[4*jb+3],q.w,a3);
      }
      // compiler memory barrier: pc[] can no longer be rematerialized
      // from LDS after this point -> must stay in VGPRs (R4's "+v" pins
      // did not have this property).
      asm volatile("" ::: "memory");
      float apq=(a0+a1)+(a2+a3);
      const bool isP = t < (t ^ m);
      float app = isP ? nrm : pn;
      float aqq = isP ? pn : nrm;
      const bool rot = (apq*apq > tolsq*app*aqq);
      if (__any((int)rot)){
        float tau = (aqq - app) / (2.0f*apq);
        float tt  = 1.0f / (fabsf(tau) + sqrtf(fmaf(tau,tau,1.0f)));
        tt = (tau < 0.0f) ? -tt : tt;
        float cc = rsqrtf(fmaf(tt,tt,1.0f));
        float ss = cc*tt;
        float ccv = rot ? cc : 1.0f;
        float sgv = rot ? (isP ? -ss : ss) : 0.0f;
#pragma unroll
        for (int j=0;j<64;j++) col[j] = fmaf(ccv, col[j], sgv*pc[j]);
        float tq = tt*apq;
        nrm += rot ? (isP ? -tq : tq) : 0.0f;
        // write back own column only if this lane actually rotated
        if (rot){
#pragma unroll
          for (int jb=0;jb<16;jb++)
            *reinterpret_cast<float4*>(Wm + t*LDP + 4*jb) =
              make_float4(col[4*jb],col[4*jb+1],col[4*jb+2],col[4*jb+3]);
        }
        anyrot = 1;
      }
    }
    if (!__any(anyrot)) break;
  }
  // exact norms at the end
  {
    float n0=0.f,n1=0.f,n2=0.f,n3=0.f;
#pragma unroll
    for (int j=0;j<64;j+=4){
      n0=fmaf(col[j+0],col[j+0],n0); n1=fmaf(col[j+1],col[j+1],n1);
      n2=fmaf(col[j+2],col[j+2],n2); n3=fmaf(col[j+3],col[j+3],n3);
    }
    nrm=(n0+n1)+(n2+n3);
  }
}

// =====================================================================
// LDS-free congruence: col = (M * Xb * M^T) column t = M * (Xb * m_t).
// Xb/M element loads are wave-uniform -> scalar pipe; z blocked 4-wide.
// =====================================================================
__device__ __forceinline__ void cong_cols(const float* __restrict__ Xb,
                                          const float* __restrict__ M,
                                          float col[64], const int t){
  float mrow[64];
#pragma unroll
  for (int j=0;j<16;j++){
    float4 v = *reinterpret_cast<const float4*>(M + t*64 + 4*j);
    mrow[4*j+0]=v.x; mrow[4*j+1]=v.y; mrow[4*j+2]=v.z; mrow[4*j+3]=v.w;
  }
#pragma unroll
  for (int i=0;i<64;i++) col[i]=0.f;
#pragma unroll 1
  for (int kb=0;kb<16;kb++){
    const float* xr = Xb + kb*256;
    float z0=0.f,z1=0.f,z2=0.f,z3=0.f;
#pragma unroll
    for (int j=0;j<64;j++){
      float mj = mrow[j];
      z0 = fmaf(xr[      j], mj, z0);
      z1 = fmaf(xr[ 64 + j], mj, z1);
      z2 = fmaf(xr[128 + j], mj, z2);
      z3 = fmaf(xr[192 + j], mj, z3);
    }
    const float* mc = M + 4*kb;
#pragma unroll
    for (int i=0;i<64;i++){
      float c = col[i];
      c = fmaf(mc[i*64+0], z0, c);
      c = fmaf(mc[i*64+1], z1, c);
      c = fmaf(mc[i*64+2], z2, c);
      c = fmaf(mc[i*64+3], z3, c);
      col[i] = c;
    }
  }
}

// ================= K1: batch mean =================
__global__ __launch_bounds__(256) void k_mean(const float* __restrict__ X, float* __restrict__ meanAcc){
  const int tid=threadIdx.x; const int blk=blockIdx.x;
  float acc[16];
#pragma unroll
  for (int j=0;j<16;j++) acc[j]=0.f;
  const float* p = X + (size_t)blk*32*4096;
  for (int b2=0;b2<32;b2++){
#pragma unroll
    for (int j=0;j<16;j++) acc[j] += p[(size_t)b2*4096 + tid + 256*j];
  }
#pragma unroll
  for (int j=0;j<16;j++) atomicAdd(&meanAcc[tid+256*j], acc[j]*(1.0f/4096.0f));
}

// ================= 256-thread LDS matmul (col-major, stride LD2) =================
template<int MODE>
__device__ __forceinline__ void mmc256(float* __restrict__ dst, const float* __restrict__ A,
                                       const float* __restrict__ B, const float p0){
  const int tid=threadIdx.x; const int t=tid&63; const int i0=(tid>>6)*16;
  float acc[16];
#pragma unroll
  for (int j=0;j<16;j++) acc[j]=0.f;
#pragma unroll 4
  for (int k=0;k<64;k++){
    float bk = B[t*LD2+k];
#pragma unroll
    for (int j=0;j<16;j++) acc[j] = fmaf(A[k*LD2+i0+j], bk, acc[j]);
  }
  __syncthreads();
#pragma unroll
  for (int j=0;j<16;j++){
    int i=i0+j;
    float v=acc[j];
    if (MODE==1) v*=0.5f;
    if (MODE==2) v = ((i==t)?3.0f:0.0f) - v;
    if (MODE==3) v = v + ((i==t)?p0:0.0f);
    dst[t*LD2+i]=v;
  }
  __syncthreads();
}

__device__ __forceinline__ void chol_lds(float* __restrict__ C, const int tid, const int t, const int g){
  for (int j=0;j<64;j++){
    if (tid<64){
      float ljj = sqrtf(C[j*LD2+j]);
      float rinv = 1.0f/ljj;
      if (tid>=j) C[j*LD2+tid] = (tid==j)? ljj : C[j*LD2+tid]*rinv;
    }
    __syncthreads();
    for (int c=j+1+g; c<64; c+=4){
      float ljc = C[j*LD2+c];
      if (t>=c) C[c*LD2+t] -= C[j*LD2+t]*ljc;
    }
    __syncthreads();
  }
}

// ================= K2: Ms = mean^{1/2}, Mis = mean^{-1/2} via Newton-Schulz ====
__global__ __launch_bounds__(256) void k_sqrtmean(const float* __restrict__ meanw,
                                                  float* __restrict__ Msg, float* __restrict__ Misg){
  __shared__ float bufY[64*LD2], bufZ[64*LD2], bufT[64*LD2];
  const int tid=threadIdx.x;
  float tr=0.f;
  for (int k=0;k<64;k++) tr += meanw[k*65];
  const float alpha = 64.0f/tr;
  for (int e=tid; e<4096; e+=256){
    int r=e>>6, c=e&63;
    bufY[c*LD2+r] = alpha*meanw[e];
    bufZ[c*LD2+r] = (r==c)?1.0f:0.0f;
  }
  __syncthreads();
  float *pY=bufY, *pZ=bufZ, *pT=bufT;
  for (int it=0; it<5; ++it){
    mmc256<2>(pT, pZ, pY, 0.f);   // T = 3I - Z*Y
    mmc256<1>(pZ, pT, pZ, 0.f);   // Z' = 0.5*T*Z
    mmc256<1>(pT, pY, pT, 0.f);   // Y' = 0.5*Y*T
    float* tm=pY; pY=pT; pT=tm;
  }
  const float sa = sqrtf(alpha);
  const float isa = 1.0f/sa;
  for (int e=tid; e<4096; e+=256){
    int r=e>>6, c=e&63;
    Msg[e]  = pY[c*LD2+r]*isa;
    Misg[e] = pZ[c*LD2+r]*sa;
  }
}

// ================= K3: accumulate log(Mis X Mis) into slots =================
__global__ __launch_bounds__(64,2) void k_logaccum(const float* __restrict__ X,
                                                   const float* __restrict__ Mis,
                                                   float* __restrict__ slots){
  __shared__ __align__(16) float Wm[64*LDP];
  __shared__ float wcoef[64];
  const int t=threadIdx.x & 63; const int b=blockIdx.x;
  float col[64]; float nrm;
  cong_cols(X + (size_t)b*4096, Mis, col, t);
  jacobi64_lds(col, nrm, Wm, t, 7, 1e-8f);
  // ensure Wm reflects final columns (lanes that skipped the last
  // writeback are unchanged in LDS already; rotated lanes wrote back).
  wcoef[t] = 0.5f*logf(nrm)/nrm;
  float acc[64];
#pragma unroll
  for (int i=0;i<64;i++) acc[i]=0.f;
#pragma unroll 1
  for (int k=0;k<64;k++){
    float f = wcoef[k]*Wm[k*LDP+t];
#pragma unroll
    for (int jj=0;jj<16;jj++){
      float4 a = *reinterpret_cast<const float4*>(&Wm[k*LDP+4*jj]);
      acc[4*jj+0]=fmaf(a.x,f,acc[4*jj+0]); acc[4*jj+1]=fmaf(a.y,f,acc[4*jj+1]);
      acc[4*jj+2]=fmaf(a.z,f,acc[4*jj+2]); acc[4*jj+3]=fmaf(a.w,f,acc[4*jj+3]);
    }
  }
  float* dst = slots + (size_t)(b & (NSLOTS-1))*4096;
#pragma unroll
  for (int i=0;i<64;i++) atomicAdd(&dst[i*64+t], acc[i]);
}

// ================= K4: exp(tang), batch_mean, chol, Linv, Lb =================
__global__ __launch_bounds__(256) void k_mid(const float* __restrict__ slots,
                                             const float* __restrict__ Msg,
                                             const float* __restrict__ bias,
                                             float* __restrict__ Linvg, float* __restrict__ Lbg){
  __shared__ float b1[64*LD2], b2[64*LD2], b3[64*LD2];
  const int tid=threadIdx.x; const int t=tid&63; const int g=tid>>6;
  for (int e=tid; e<4096; e+=256){
    float s=0.f;
    for (int sl=0; sl<NSLOTS; ++sl) s += slots[(size_t)sl*4096+e];
    b1[(e&63)*LD2+(e>>6)] = s * (1.0f/(4096.0f*16.0f));
  }
  __syncthreads();
  for (int e=tid; e<4096; e+=256){
    int r=e>>6, c=e&63;
    b2[c*LD2+r] = (1.0f/40320.0f)*b1[c*LD2+r] + ((r==c)?(1.0f/5040.0f):0.0f);
  }
  __syncthreads();
  float *pR=b2, *pT=b3;
  const float cj0=1.f/720.f, cj1=1.f/120.f, cj2=1.f/24.f, cj3=1.f/6.f, cj4=0.5f, cj5=1.f, cj6=1.f;
  mmc256<3>(pT,b1,pR,cj0); { float* tm=pR; pR=pT; pT=tm; }
  mmc256<3>(pT,b1,pR,cj1); { float* tm=pR; pR=pT; pT=tm; }
  mmc256<3>(pT,b1,pR,cj2); { float* tm=pR; pR=pT; pT=tm; }
  mmc256<3>(pT,b1,pR,cj3); { float* tm=pR; pR=pT; pT=tm; }
  mmc256<3>(pT,b1,pR,cj4); { float* tm=pR; pR=pT; pT=tm; }
  mmc256<3>(pT,b1,pR,cj5); { float* tm=pR; pR=pT; pT=tm; }
  mmc256<3>(pT,b1,pR,cj6); { float* tm=pR; pR=pT; pT=tm; }
  for (int q=0;q<4;q++){ mmc256<0>(pT, pR, pR, 0.f); float* tm=pR; pR=pT; pT=tm; }
  for (int e=tid; e<4096; e+=256) b1[(e&63)*LD2+(e>>6)] = Msg[e];
  __syncthreads();
  mmc256<0>(pT, b1, pR, 0.f);
  mmc256<0>(pR, pT, b1, 0.f);
  chol_lds(pR, tid, t, g);
  if (tid<64){
    const int c=tid;
    for (int k=0;k<64;k++) pT[c*LD2+k]=0.f;
    for (int i=0;i<64;i++){
      float s = (i==c)?1.0f:0.0f;
      for (int k=0;k<i;k++) s -= pR[k*LD2+i]*pT[c*LD2+k];
      pT[c*LD2+i] = s / pR[i*LD2+i];
    }
  }
  __syncthreads();
  if (tid<64){
    const int c=tid;
    for (int i=0;i<64;i++) Linvg[i*64+c] = pT[c*LD2+i];
  }
  for (int e=tid; e<4096; e+=256) b1[(e&63)*LD2+(e>>6)] = bias[e];
  __syncthreads();
  chol_lds(b1, tid, t, g);
  if (tid<64){
    const int c=tid;
    for (int i=0;i<64;i++) Lbg[i*64+c] = (c<=i)? b1[c*LD2+i] : 0.0f;
  }
}

// ================= K5: Xc eig, var accumulation, optional store =================
template<bool STORE>
__global__ __launch_bounds__(64,2) void k_center(const float* __restrict__ X,
                                                 const float* __restrict__ Linv,
                                                 float* __restrict__ varAcc,
                                                 float* __restrict__ Qs, float* __restrict__ Ls){
  __shared__ __align__(16) float Wm[64*LDP];
  const int t=threadIdx.x & 63; const int b=blockIdx.x;
  float col[64]; float nrm;
  cong_cols(X + (size_t)b*4096, Linv, col, t);
  jacobi64_lds(col, nrm, Wm, t, 10, 1e-10f);
  float ll = 0.5f*logf(nrm);
  float f2 = ll*ll;
#pragma unroll
  for (int off=1; off<64; off<<=1) f2 += __shfl_xor(f2, off, 64);
  if (t==0) atomicAdd(varAcc, f2);
  if (STORE){
#pragma unroll
    for (int j=0;j<16;j++)
      *reinterpret_cast<float4*>(Qs + (size_t)b*4096 + t*64 + 4*j) =
          make_float4(col[4*j],col[4*j+1],col[4*j+2],col[4*j+3]);
    Ls[(size_t)b*64+t] = nrm;
  }
}

// ================= K7: Xs = sum lam^f q q^T ; out = Lb Xs Lb^T =================
template<bool LOADW>
__global__ __launch_bounds__(64,2) void k_out(const float* __restrict__ X,
                                              const float* __restrict__ Linv,
                                              const float* __restrict__ Qs,
                                              const float* __restrict__ Ls,
                                              const float* __restrict__ Lb,
                                              const float* __restrict__ varAcc,
                                              const float* __restrict__ shift,
                                              float* __restrict__ out){
  __shared__ __align__(16) float Wm[64*LDP];
  __shared__ float wcoef[64];
  const int t=threadIdx.x & 63; const int b=blockIdx.x;
  float col[64]; float nrm;
  if (LOADW){
#pragma unroll
    for (int j=0;j<16;j++){
      float4 v = *reinterpret_cast<const float4*>(Qs + (size_t)b*4096 + t*64 + 4*j);
      col[4*j+0]=v.x; col[4*j+1]=v.y; col[4*j+2]=v.z; col[4*j+3]=v.w;
    }
    nrm = Ls[(size_t)b*64+t];
#pragma unroll
    for (int j=0;j<16;j++)
      *reinterpret_cast<float4*>(&Wm[t*LDP+4*j]) = make_float4(col[4*j],col[4*j+1],col[4*j+2],col[4*j+3]);
  } else {
    cong_cols(X + (size_t)b*4096, Linv, col, t);
    jacobi64_lds(col, nrm, Wm, t, 10, 1e-10f);
  }
  const float var = varAcc[0] * (1.0f/4096.0f);
  const float factor = shift[0] * rsqrtf(var + 1e-5f);
  wcoef[t] = expf((factor-2.0f)*0.5f*logf(nrm));   // lam^{f-2}
  float acc[64];
#pragma unroll
  for (int i=0;i<64;i++) acc[i]=0.f;
#pragma unroll 1
  for (int k=0;k<64;k++){
    float f = wcoef[k]*Wm[k*LDP+t];
#pragma unroll
    for (int jj=0;jj<16;jj++){
      float4 a = *reinterpret_cast<const float4*>(&Wm[k*LDP+4*jj]);
      acc[4*jj+0]=fmaf(a.x,f,acc[4*jj+0]); acc[4*jj+1]=fmaf(a.y,f,acc[4*jj+1]);
      acc[4*jj+2]=fmaf(a.z,f,acc[4*jj+2]); acc[4*jj+3]=fmaf(a.w,f,acc[4*jj+3]);
    }
  }
  // T2 = Lb * Xs (col-major into Wm; single-wave block so all Wm reads
  // above complete before the overwrite below)
#pragma unroll 2
  for (int i=0;i<64;i++){
    float s0=0.f,s1=0.f;
#pragma unroll
    for (int k=0;k<64;k+=2){ s0=fmaf(Lb[i*64+k],acc[k],s0); s1=fmaf(Lb[i*64+k+1],acc[k+1],s1); }
    Wm[t*LDP+i]=s0+s1;
  }
  float o[64];
#pragma unroll
  for (int i=0;i<64;i++) o[i]=0.f;
#pragma unroll 1
  for (int k=0;k<64;k++){
    float bk = Lb[t*64+k];
#pragma unroll
    for (int jj=0;jj<16;jj++){
      float4 a = *reinterpret_cast<const float4*>(&Wm[k*LDP+4*jj]);
      o[4*jj+0]=fmaf(a.x,bk,o[4*jj+0]); o[4*jj+1]=fmaf(a.y,bk,o[4*jj+1]);
      o[4*jj+2]=fmaf(a.z,bk,o[4*jj+2]); o[4*jj+3]=fmaf(a.w,bk,o[4*jj+3]);
    }
  }
  float* ob = out + (size_t)b*4096;
#pragma unroll
  for (int i=0;i<64;i++) ob[i*64+t] = o[i];
}

// =====================================================================
extern "C" void kernel_launch(void* const* d_in, const int* in_sizes, int n_in,
                              void* d_out, int out_size, void* d_ws, size_t ws_size,
                              hipStream_t stream){
  (void)in_sizes; (void)n_in; (void)out_size;
  const float* X     = (const float*)d_in[0];
  const float* bias  = (const float*)d_in[1];
  const float* shift = (const float*)d_in[2];
  float* out = (float*)d_out;
  float* ws  = (float*)d_ws;

  hipMemsetAsync(d_ws, 0, (size_t)WS_ZERO_FLOATS*sizeof(float), stream);
  k_mean<<<128,256,0,stream>>>(X, ws+OFF_MEAN);
  k_sqrtmean<<<1,256,0,stream>>>(ws+OFF_MEAN, ws+OFF_MS, ws+OFF_MIS);
  k_logaccum<<<NB,64,0,stream>>>(X, ws+OFF_MIS, ws+OFF_SLOTS);
  k_mid<<<1,256,0,stream>>>(ws+OFF_SLOTS, ws+OFF_MS, bias, ws+OFF_LINV, ws+OFF_LB);

  const bool big = ws_size >= (size_t)WS_FULL*sizeof(float);
  if (big){
    k_center<true><<<NB,64,0,stream>>>(X, ws+OFF_LINV, ws+OFF_VAR, ws+OFF_Q, ws+OFF_LAM);
    k_out<true><<<NB,64,0,stream>>>(X, ws+OFF_LINV, ws+OFF_Q, ws+OFF_LAM, ws+OFF_LB, ws+OFF_VAR, shift, out);
  } else {
    k_center<false><<<NB,64,0,stream>>>(X, ws+OFF_LINV, ws+OFF_VAR, nullptr, nullptr);
    k_out<false><<<NB,64,0,stream>>>(X, ws+OFF_LINV, nullptr, nullptr, ws+OFF_LB, ws+OFF_VAR, shift, out);
  }
}

// Round 10
// 3000.379 us; speedup vs baseline: 4.5451x; 1.4252x over previous
//
#include <hip/hip_runtime.h>
#include <cstdint>
#include <cstddef>

#define NB 4096
#define NN 64
#define LDP 68   // LDS stride: 272B = 16B-aligned, spreads lanes over bank-quads
#define LD2 65   // single-block kernels: LDS stride (scalar access, conflict-free)

// ---- workspace float offsets ----
#define OFF_MEAN  0
#define OFF_MS    4096
#define OFF_MIS   8192
#define OFF_LINV  12288
#define OFF_LB    16384
#define OFF_VAR   20480
#define OFF_SLOTS 24576
#define NSLOTS    32
#define OFF_C     (OFF_SLOTS + NSLOTS*4096)        // 155648 (C = Linv*Ms)
#define WS_ZERO_FLOATS (OFF_SLOTS + NSLOTS*4096)   // zero slots+var region
#define OFF_Q     286720                            // keep legacy layout
#define OFF_LAM   (OFF_Q + (size_t)NB*4096)
#define WS_FULL   (OFF_LAM + (size_t)NB*64)

__device__ __forceinline__ float bperm(int pad, float v){
  return __int_as_float(__builtin_amdgcn_ds_bpermute(pad, __float_as_int(v)));
}

// =====================================================================
// One-sided Jacobi with LDS master copy (col-major, stride LDP).
// Skip-round = 16 b128 reads + 1 bperm; rotating round adds conditional
// write-back. Warm starts make most rounds skip-rounds.
// =====================================================================
__device__ __forceinline__ void jacobi64_lds(float col[64], float& nrm,
                                             float* __restrict__ Wm,
                                             const int t,
                                             const int maxsweep, const float tolsq) {
  {
#pragma unroll
    for (int jb=0;jb<16;jb++)
      *reinterpret_cast<float4*>(Wm + t*LDP + 4*jb) =
        make_float4(col[4*jb],col[4*jb+1],col[4*jb+2],col[4*jb+3]);
    float n0=0.f,n1=0.f,n2=0.f,n3=0.f;
#pragma unroll
    for (int j=0;j<64;j+=4){
      n0=fmaf(col[j+0],col[j+0],n0); n1=fmaf(col[j+1],col[j+1],n1);
      n2=fmaf(col[j+2],col[j+2],n2); n3=fmaf(col[j+3],col[j+3],n3);
    }
    nrm=(n0+n1)+(n2+n3);
  }
#pragma unroll 1
  for (int sw=0; sw<maxsweep; ++sw){
    int anyrot=0;
#pragma unroll 1
    for (int m=1; m<64; ++m){
      const int pad = ((t ^ m) << 2);
      const float* __restrict__ P = Wm + (t ^ m)*LDP;
      float pn = bperm(pad, nrm);
      float pc[64];
      float a0=0.f,a1=0.f,a2=0.f,a3=0.f;
#pragma unroll
      for (int jb=0;jb<16;jb++){
        float4 q = *reinterpret_cast<const float4*>(P + 4*jb);
        pc[4*jb+0]=q.x; pc[4*jb+1]=q.y; pc[4*jb+2]=q.z; pc[4*jb+3]=q.w;
        a0=fmaf(col[4*jb+0],q.x,a0); a1=fmaf(col[4*jb+1],q.y,a1);
        a2=fmaf(col[4*jb+2],q.z,a2); a3=fmaf(col[4*jb+3],q.w,a3);
      }
      asm volatile("" ::: "memory");
      float apq=(a0+a1)+(a2+a3);
      const bool isP = t < (t ^ m);
      float app = isP ? nrm : pn;
      float aqq = isP ? pn : nrm;
      const bool rot = (apq*apq > tolsq*app*aqq);
      if (__any((int)rot)){
        float tau = (aqq - app) / (2.0f*apq);
        float tt  = 1.0f / (fabsf(tau) + sqrtf(fmaf(tau,tau,1.0f)));
        tt = (tau < 0.0f) ? -tt : tt;
        float cc = rsqrtf(fmaf(tt,tt,1.0f));
        float ss = cc*tt;
        float ccv = rot ? cc : 1.0f;
        float sgv = rot ? (isP ? -ss : ss) : 0.0f;
#pragma unroll
        for (int j=0;j<64;j++) col[j] = fmaf(ccv, col[j], sgv*pc[j]);
        float tq = tt*apq;
        nrm += rot ? (isP ? -tq : tq) : 0.0f;
        if (rot){
#pragma unroll
          for (int jb=0;jb<16;jb++)
            *reinterpret_cast<float4*>(Wm + t*LDP + 4*jb) =
              make_float4(col[4*jb],col[4*jb+1],col[4*jb+2],col[4*jb+3]);
        }
        anyrot = 1;
      }
    }
    if (!__any(anyrot)) break;
  }
  {
    float n0=0.f,n1=0.f,n2=0.f,n3=0.f;
#pragma unroll
    for (int j=0;j<64;j+=4){
      n0=fmaf(col[j+0],col[j+0],n0); n1=fmaf(col[j+1],col[j+1],n1);
      n2=fmaf(col[j+2],col[j+2],n2); n3=fmaf(col[j+3],col[j+3],n3);
    }
    nrm=(n0+n1)+(n2+n3);
  }
}

// =====================================================================
// LDS-free congruence: col = (M * Xb * M^T) column t = M * (Xb * m_t).
// =====================================================================
__device__ __forceinline__ void cong_cols(const float* __restrict__ Xb,
                                          const float* __restrict__ M,
                                          float col[64], const int t){
  float mrow[64];
#pragma unroll
  for (int j=0;j<16;j++){
    float4 v = *reinterpret_cast<const float4*>(M + t*64 + 4*j);
    mrow[4*j+0]=v.x; mrow[4*j+1]=v.y; mrow[4*j+2]=v.z; mrow[4*j+3]=v.w;
  }
#pragma unroll
  for (int i=0;i<64;i++) col[i]=0.f;
#pragma unroll 1
  for (int kb=0;kb<16;kb++){
    const float* xr = Xb + kb*256;
    float z0=0.f,z1=0.f,z2=0.f,z3=0.f;
#pragma unroll
    for (int j=0;j<64;j++){
      float mj = mrow[j];
      z0 = fmaf(xr[      j], mj, z0);
      z1 = fmaf(xr[ 64 + j], mj, z1);
      z2 = fmaf(xr[128 + j], mj, z2);
      z3 = fmaf(xr[192 + j], mj, z3);
    }
    const float* mc = M + 4*kb;
#pragma unroll
    for (int i=0;i<64;i++){
      float c = col[i];
      c = fmaf(mc[i*64+0], z0, c);
      c = fmaf(mc[i*64+1], z1, c);
      c = fmaf(mc[i*64+2], z2, c);
      c = fmaf(mc[i*64+3], z3, c);
      col[i] = c;
    }
  }
}

// ================= K1: batch mean =================
__global__ __launch_bounds__(256) void k_mean(const float* __restrict__ X, float* __restrict__ meanAcc){
  const int tid=threadIdx.x; const int blk=blockIdx.x;
  float acc[16];
#pragma unroll
  for (int j=0;j<16;j++) acc[j]=0.f;
  const float* p = X + (size_t)blk*32*4096;
  for (int b2=0;b2<32;b2++){
#pragma unroll
    for (int j=0;j<16;j++) acc[j] += p[(size_t)b2*4096 + tid + 256*j];
  }
#pragma unroll
  for (int j=0;j<16;j++) atomicAdd(&meanAcc[tid+256*j], acc[j]*(1.0f/4096.0f));
}

// ================= 256-thread LDS matmul (col-major, stride LD2) =================
template<int MODE>
__device__ __forceinline__ void mmc256(float* __restrict__ dst, const float* __restrict__ A,
                                       const float* __restrict__ B, const float p0){
  const int tid=threadIdx.x; const int t=tid&63; const int i0=(tid>>6)*16;
  float acc[16];
#pragma unroll
  for (int j=0;j<16;j++) acc[j]=0.f;
#pragma unroll 4
  for (int k=0;k<64;k++){
    float bk = B[t*LD2+k];
#pragma unroll
    for (int j=0;j<16;j++) acc[j] = fmaf(A[k*LD2+i0+j], bk, acc[j]);
  }
  __syncthreads();
#pragma unroll
  for (int j=0;j<16;j++){
    int i=i0+j;
    float v=acc[j];
    if (MODE==1) v*=0.5f;
    if (MODE==2) v = ((i==t)?3.0f:0.0f) - v;
    if (MODE==3) v = v + ((i==t)?p0:0.0f);
    dst[t*LD2+i]=v;
  }
  __syncthreads();
}

__device__ __forceinline__ void chol_lds(float* __restrict__ C, const int tid, const int t, const int g){
  for (int j=0;j<64;j++){
    if (tid<64){
      float ljj = sqrtf(C[j*LD2+j]);
      float rinv = 1.0f/ljj;
      if (tid>=j) C[j*LD2+tid] = (tid==j)? ljj : C[j*LD2+tid]*rinv;
    }
    __syncthreads();
    for (int c=j+1+g; c<64; c+=4){
      float ljc = C[j*LD2+c];
      if (t>=c) C[c*LD2+t] -= C[j*LD2+t]*ljc;
    }
    __syncthreads();
  }
}

// ================= K2: Ms = mean^{1/2}, Mis = mean^{-1/2} via Newton-Schulz ====
__global__ __launch_bounds__(256) void k_sqrtmean(const float* __restrict__ meanw,
                                                  float* __restrict__ Msg, float* __restrict__ Misg){
  __shared__ float bufY[64*LD2], bufZ[64*LD2], bufT[64*LD2];
  const int tid=threadIdx.x;
  float tr=0.f;
  for (int k=0;k<64;k++) tr += meanw[k*65];
  const float alpha = 64.0f/tr;
  for (int e=tid; e<4096; e+=256){
    int r=e>>6, c=e&63;
    bufY[c*LD2+r] = alpha*meanw[e];
    bufZ[c*LD2+r] = (r==c)?1.0f:0.0f;
  }
  __syncthreads();
  float *pY=bufY, *pZ=bufZ, *pT=bufT;
  for (int it=0; it<5; ++it){
    mmc256<2>(pT, pZ, pY, 0.f);   // T = 3I - Z*Y
    mmc256<1>(pZ, pT, pZ, 0.f);   // Z' = 0.5*T*Z
    mmc256<1>(pT, pY, pT, 0.f);   // Y' = 0.5*Y*T
    float* tm=pY; pY=pT; pT=tm;
  }
  const float sa = sqrtf(alpha);
  const float isa = 1.0f/sa;
  for (int e=tid; e<4096; e+=256){
    int r=e>>6, c=e&63;
    Msg[e]  = pY[c*LD2+r]*isa;
    Misg[e] = pZ[c*LD2+r]*sa;
  }
}

// ================= K3: accumulate log(Mis X Mis) into slots =================
// Phase-1 tol/maxsweep = R5-PASSING config (1e-8, 7): R9's loosening to
// (1e-6, 5) failed because warm-start fidelity is NOT independent of
// phase-1 convergence -- the residual enters Xc undamped via the
// estimated-lambda rescale. Q/lam stored for phase-2 warm start.
template<bool STOREQ>
__global__ __launch_bounds__(64,2) void k_logaccum(const float* __restrict__ X,
                                                   const float* __restrict__ Mis,
                                                   float* __restrict__ slots,
                                                   float* __restrict__ Qs,
                                                   float* __restrict__ Ls){
  __shared__ __align__(16) float Wm[64*LDP];
  __shared__ float wcoef[64];
  const int t=threadIdx.x & 63; const int b=blockIdx.x;
  float col[64]; float nrm;
  cong_cols(X + (size_t)b*4096, Mis, col, t);
  jacobi64_lds(col, nrm, Wm, t, 7, 1e-8f);
  if (STOREQ){
#pragma unroll
    for (int j=0;j<16;j++)
      *reinterpret_cast<float4*>(Qs + (size_t)b*4096 + t*64 + 4*j) =
          make_float4(col[4*j],col[4*j+1],col[4*j+2],col[4*j+3]);
    Ls[(size_t)b*64+t] = nrm;
  }
  wcoef[t] = 0.5f*logf(nrm)/nrm;
  float acc[64];
#pragma unroll
  for (int i=0;i<64;i++) acc[i]=0.f;
#pragma unroll 1
  for (int k=0;k<64;k++){
    float f = wcoef[k]*Wm[k*LDP+t];
#pragma unroll
    for (int jj=0;jj<16;jj++){
      float4 a = *reinterpret_cast<const float4*>(&Wm[k*LDP+4*jj]);
      acc[4*jj+0]=fmaf(a.x,f,acc[4*jj+0]); acc[4*jj+1]=fmaf(a.y,f,acc[4*jj+1]);
      acc[4*jj+2]=fmaf(a.z,f,acc[4*jj+2]); acc[4*jj+3]=fmaf(a.w,f,acc[4*jj+3]);
    }
  }
  float* dst = slots + (size_t)(b & (NSLOTS-1))*4096;
#pragma unroll
  for (int i=0;i<64;i++) atomicAdd(&dst[i*64+t], acc[i]);
}

// ================= K4: exp(tang), batch_mean, chol, Linv, Lb, C=Linv*Ms ======
__global__ __launch_bounds__(256) void k_mid(const float* __restrict__ slots,
                                             const float* __restrict__ Msg,
                                             const float* __restrict__ bias,
                                             float* __restrict__ Linvg, float* __restrict__ Lbg,
                                             float* __restrict__ Cg){
  __shared__ float b1[64*LD2], b2[64*LD2], b3[64*LD2];
  const int tid=threadIdx.x; const int t=tid&63; const int g=tid>>6;
  for (int e=tid; e<4096; e+=256){
    float s=0.f;
    for (int sl=0; sl<NSLOTS; ++sl) s += slots[(size_t)sl*4096+e];
    b1[(e&63)*LD2+(e>>6)] = s * (1.0f/(4096.0f*16.0f));
  }
  __syncthreads();
  for (int e=tid; e<4096; e+=256){
    int r=e>>6, c=e&63;
    b2[c*LD2+r] = (1.0f/40320.0f)*b1[c*LD2+r] + ((r==c)?(1.0f/5040.0f):0.0f);
  }
  __syncthreads();
  float *pR=b2, *pT=b3;
  const float cj0=1.f/720.f, cj1=1.f/120.f, cj2=1.f/24.f, cj3=1.f/6.f, cj4=0.5f, cj5=1.f, cj6=1.f;
  mmc256<3>(pT,b1,pR,cj0); { float* tm=pR; pR=pT; pT=tm; }
  mmc256<3>(pT,b1,pR,cj1); { float* tm=pR; pR=pT; pT=tm; }
  mmc256<3>(pT,b1,pR,cj2); { float* tm=pR; pR=pT; pT=tm; }
  mmc256<3>(pT,b1,pR,cj3); { float* tm=pR; pR=pT; pT=tm; }
  mmc256<3>(pT,b1,pR,cj4); { float* tm=pR; pR=pT; pT=tm; }
  mmc256<3>(pT,b1,pR,cj5); { float* tm=pR; pR=pT; pT=tm; }
  mmc256<3>(pT,b1,pR,cj6); { float* tm=pR; pR=pT; pT=tm; }
  for (int q=0;q<4;q++){ mmc256<0>(pT, pR, pR, 0.f); float* tm=pR; pR=pT; pT=tm; }
  for (int e=tid; e<4096; e+=256) b1[(e&63)*LD2+(e>>6)] = Msg[e];
  __syncthreads();
  mmc256<0>(pT, b1, pR, 0.f);   // T = Ms*E
  mmc256<0>(pR, pT, b1, 0.f);   // bm = T*Ms
  chol_lds(pR, tid, t, g);      // pR holds L (lower, col-major)
  if (tid<64){
    const int c=tid;
    for (int k=0;k<64;k++) pT[c*LD2+k]=0.f;
    for (int i=0;i<64;i++){
      float s = (i==c)?1.0f:0.0f;
      for (int k=0;k<i;k++) s -= pR[k*LD2+i]*pT[c*LD2+k];
      pT[c*LD2+i] = s / pR[i*LD2+i];
    }
  }
  __syncthreads();
  if (tid<64){
    const int c=tid;
    for (int i=0;i<64;i++) Linvg[i*64+c] = pT[c*LD2+i];
  }
  // C = Linv * Ms  (pT holds Linv col-major, b1 holds Ms col-major)
  mmc256<0>(pR, pT, b1, 0.f);   // pR[t*LD2+i] = C[i][t]
  for (int e=tid; e<4096; e+=256) Cg[e] = pR[(e&63)*LD2+(e>>6)];  // row-major
  for (int e=tid; e<4096; e+=256) b1[(e&63)*LD2+(e>>6)] = bias[e];
  __syncthreads();
  chol_lds(b1, tid, t, g);
  if (tid<64){
    const int c=tid;
    for (int i=0;i<64;i++) Lbg[i*64+c] = (c<=i)? b1[c*LD2+i] : 0.0f;
  }
}

// ================= K5: Xc eig via warm start, var accumulation =================
// WARM: W0 col t = C * (lam_t^{1/2} q_t). W0^T W0 = Lam^{1/2} V^T exp(-tang)
// V Lam^{1/2} -> off-diag ~ ||tang - cI|| ~ 0.03 -> ~3-4 sweeps vs ~9 cold.
// Xc fidelity = phase-1 residual (~1e-4 at tolsq 1e-8), negligible.
template<bool WARM>
__global__ __launch_bounds__(64,2) void k_center(const float* __restrict__ X,
                                                 const float* __restrict__ Linv,
                                                 const float* __restrict__ Cg,
                                                 float* __restrict__ varAcc,
                                                 float* __restrict__ Qs, float* __restrict__ Ls){
  __shared__ __align__(16) float Wm[64*LDP];
  const int t=threadIdx.x & 63; const int b=blockIdx.x;
  float col[64]; float nrm;
  if (WARM){
    const float s = rsqrtf(sqrtf(Ls[(size_t)b*64+t]));   // lam^{-1/2} (nrm=lam^2)
    const float* q1 = Qs + (size_t)b*4096 + t*64;
#pragma unroll
    for (int i=0;i<64;i++) col[i]=0.f;
#pragma unroll 1
    for (int kb=0;kb<16;kb++){
      float4 v = *reinterpret_cast<const float4*>(q1 + 4*kb);
      float x0=v.x*s, x1=v.y*s, x2=v.z*s, x3=v.w*s;
      const float* cc = Cg + 4*kb;
#pragma unroll
      for (int i=0;i<64;i++){
        float c = col[i];
        c = fmaf(cc[i*64+0], x0, c);
        c = fmaf(cc[i*64+1], x1, c);
        c = fmaf(cc[i*64+2], x2, c);
        c = fmaf(cc[i*64+3], x3, c);
        col[i] = c;
      }
    }
    jacobi64_lds(col, nrm, Wm, t, 8, 1e-10f);
  } else {
    cong_cols(X + (size_t)b*4096, Linv, col, t);
    jacobi64_lds(col, nrm, Wm, t, 10, 1e-10f);
  }
  float ll = 0.5f*logf(nrm);
  float f2 = ll*ll;
#pragma unroll
  for (int off=1; off<64; off<<=1) f2 += __shfl_xor(f2, off, 64);
  if (t==0) atomicAdd(varAcc, f2);
  if (WARM){
#pragma unroll
    for (int j=0;j<16;j++)
      *reinterpret_cast<float4*>(Qs + (size_t)b*4096 + t*64 + 4*j) =
          make_float4(col[4*j],col[4*j+1],col[4*j+2],col[4*j+3]);
    Ls[(size_t)b*64+t] = nrm;
  }
}

// ================= K7: Xs = sum lam^f q q^T ; out = Lb Xs Lb^T =================
template<bool LOADW>
__global__ __launch_bounds__(64,2) void k_out(const float* __restrict__ X,
                                              const float* __restrict__ Linv,
                                              const float* __restrict__ Qs,
                                              const float* __restrict__ Ls,
                                              const float* __restrict__ Lb,
                                              const float* __restrict__ varAcc,
                                              const float* __restrict__ shift,
                                              float* __restrict__ out){
  __shared__ __align__(16) float Wm[64*LDP];
  __shared__ float wcoef[64];
  const int t=threadIdx.x & 63; const int b=blockIdx.x;
  float col[64]; float nrm;
  if (LOADW){
#pragma unroll
    for (int j=0;j<16;j++){
      float4 v = *reinterpret_cast<const float4*>(Qs + (size_t)b*4096 + t*64 + 4*j);
      col[4*j+0]=v.x; col[4*j+1]=v.y; col[4*j+2]=v.z; col[4*j+3]=v.w;
    }
    nrm = Ls[(size_t)b*64+t];
#pragma unroll
    for (int j=0;j<16;j++)
      *reinterpret_cast<float4*>(&Wm[t*LDP+4*j]) = make_float4(col[4*j],col[4*j+1],col[4*j+2],col[4*j+3]);
  } else {
    cong_cols(X + (size_t)b*4096, Linv, col, t);
    jacobi64_lds(col, nrm, Wm, t, 10, 1e-10f);
  }
  const float var = varAcc[0] * (1.0f/4096.0f);
  const float factor = shift[0] * rsqrtf(var + 1e-5f);
  wcoef[t] = expf((factor-2.0f)*0.5f*logf(nrm));   // lam^{f-2}
  float acc[64];
#pragma unroll
  for (int i=0;i<64;i++) acc[i]=0.f;
#pragma unroll 1
  for (int k=0;k<64;k++){
    float f = wcoef[k]*Wm[k*LDP+t];
#pragma unroll
    for (int jj=0;jj<16;jj++){
      float4 a = *reinterpret_cast<const float4*>(&Wm[k*LDP+4*jj]);
      acc[4*jj+0]=fmaf(a.x,f,acc[4*jj+0]); acc[4*jj+1]=fmaf(a.y,f,acc[4*jj+1]);
      acc[4*jj+2]=fmaf(a.z,f,acc[4*jj+2]); acc[4*jj+3]=fmaf(a.w,f,acc[4*jj+3]);
    }
  }
  // T2 = Lb * Xs (single-wave block: all Wm reads above complete first)
#pragma unroll 2
  for (int i=0;i<64;i++){
    float s0=0.f,s1=0.f;
#pragma unroll
    for (int k=0;k<64;k+=2){ s0=fmaf(Lb[i*64+k],acc[k],s0); s1=fmaf(Lb[i*64+k+1],acc[k+1],s1); }
    Wm[t*LDP+i]=s0+s1;
  }
  float o[64];
#pragma unroll
  for (int i=0;i<64;i++) o[i]=0.f;
#pragma unroll 1
  for (int k=0;k<64;k++){
    float bk = Lb[t*64+k];
#pragma unroll
    for (int jj=0;jj<16;jj++){
      float4 a = *reinterpret_cast<const float4*>(&Wm[k*LDP+4*jj]);
      o[4*jj+0]=fmaf(a.x,bk,o[4*jj+0]); o[4*jj+1]=fmaf(a.y,bk,o[4*jj+1]);
      o[4*jj+2]=fmaf(a.z,bk,o[4*jj+2]); o[4*jj+3]=fmaf(a.w,bk,o[4*jj+3]);
    }
  }
  float* ob = out + (size_t)b*4096;
#pragma unroll
  for (int i=0;i<64;i++) ob[i*64+t] = o[i];
}

// =====================================================================
extern "C" void kernel_launch(void* const* d_in, const int* in_sizes, int n_in,
                              void* d_out, int out_size, void* d_ws, size_t ws_size,
                              hipStream_t stream){
  (void)in_sizes; (void)n_in; (void)out_size;
  const float* X     = (const float*)d_in[0];
  const float* bias  = (const float*)d_in[1];
  const float* shift = (const float*)d_in[2];
  float* out = (float*)d_out;
  float* ws  = (float*)d_ws;

  hipMemsetAsync(d_ws, 0, (size_t)WS_ZERO_FLOATS*sizeof(float), stream);
  k_mean<<<128,256,0,stream>>>(X, ws+OFF_MEAN);
  k_sqrtmean<<<1,256,0,stream>>>(ws+OFF_MEAN, ws+OFF_MS, ws+OFF_MIS);

  const bool big = ws_size >= (size_t)WS_FULL*sizeof(float);
  if (big){
    k_logaccum<true><<<NB,64,0,stream>>>(X, ws+OFF_MIS, ws+OFF_SLOTS, ws+OFF_Q, ws+OFF_LAM);
    k_mid<<<1,256,0,stream>>>(ws+OFF_SLOTS, ws+OFF_MS, bias, ws+OFF_LINV, ws+OFF_LB, ws+OFF_C);
    k_center<true><<<NB,64,0,stream>>>(X, ws+OFF_LINV, ws+OFF_C, ws+OFF_VAR, ws+OFF_Q, ws+OFF_LAM);
    k_out<true><<<NB,64,0,stream>>>(X, ws+OFF_LINV, ws+OFF_Q, ws+OFF_LAM, ws+OFF_LB, ws+OFF_VAR, shift, out);
  } else {
    k_logaccum<false><<<NB,64,0,stream>>>(X, ws+OFF_MIS, ws+OFF_SLOTS, nullptr, nullptr);
    k_mid<<<1,256,0,stream>>>(ws+OFF_SLOTS, ws+OFF_MS, bias, ws+OFF_LINV, ws+OFF_LB, ws+OFF_C);
    k_center<false><<<NB,64,0,stream>>>(X, ws+OFF_LINV, nullptr, ws+OFF_VAR, nullptr, nullptr);
    k_out<false><<<NB,64,0,stream>>>(X, ws+OFF_LINV, nullptr, nullptr, ws+OFF_LB, ws+OFF_VAR, shift, out);
  }
}